// Round 15
// baseline (222.651 us; speedup 1.0000x reference)
//
#include <hip/hip_runtime.h>
#include <hip/hip_bf16.h>
#include <math.h>

#define N_NODES 50000
#define N_EDGES 800000
#define IN_CH 128
#define HID 64
#define HEADS 4
#define OUT_CH 10
#define N_GRAPHS 512
#define NEG_SLOPE 0.2f

#define ETOT_C (N_EDGES + N_NODES)          // 850000
#define NPB 128                              // nodes per bucket
#define NBUK ((N_NODES + NPB - 1) / NPB)     // 391 buckets
#define EPB 2048                             // edges per pass-A/B block
#define GA ((ETOT_C + EPB - 1) / EPB)        // 416 passA/passB blocks
#define GB1 ((N_NODES + 63) / 64)            // 782 gemm1 blocks
#define GZ 32                                // pooled-zero blocks
#define GW 192                               // convw blocks
#define HPB (N_NODES / 4)                    // 12500 agg1 blocks per head-pair

using short8_t = __attribute__((ext_vector_type(8))) short;
using f32x4 = __attribute__((ext_vector_type(4))) float;

__device__ __forceinline__ float b2f(unsigned short u) {
    return __uint_as_float(((unsigned)u) << 16);
}
__device__ __forceinline__ unsigned short f2b(float f) {
    __hip_bfloat16 b = __float2bfloat16(f);
    return *(unsigned short*)&b;
}
__device__ __forceinline__ short f2bs(float f) {
    __hip_bfloat16 b = __float2bfloat16(f);
    return *(short*)&b;
}
__device__ __forceinline__ float lrelu(float x) { return x > 0.f ? x : NEG_SLOPE * x; }

// ---- MEGA A: passA bucket-count || cntg || pooled-zero || convw ----
__global__ __launch_bounds__(256) void megaA_k(
        const int* __restrict__ dst, unsigned* __restrict__ bcnt,
        const int* __restrict__ batch, float* __restrict__ cntf,
        float* __restrict__ pooled,
        const float* __restrict__ W1, const float* __restrict__ W2,
        unsigned short* __restrict__ Wt1, unsigned short* __restrict__ Wt2) {
    int b = blockIdx.x;
    int t = threadIdx.x;
    if (b < GA) {
        __shared__ unsigned bins[NBUK];
        for (int i = t; i < NBUK; i += 256) bins[i] = 0;
        __syncthreads();
        int e0 = b * EPB;
        int e1 = min(e0 + EPB, ETOT_C);
        for (int i = e0 + t; i < e1; i += 256) {
            int d = (i < N_EDGES) ? dst[i] : i - N_EDGES;
            atomicAdd(&bins[d >> 7], 1u);
        }
        __syncthreads();
        for (int i = t; i < NBUK; i += 256)
            if (bins[i]) atomicAdd(&bcnt[i], bins[i]);
        return;
    }
    b -= GA;
    if (b < 2) {
        int g = b * 256 + t;
        if (g >= N_GRAPHS) return;
        int lo = 0, hi = N_NODES;
        while (lo < hi) { int mid = (lo + hi) >> 1; if (batch[mid] < g) lo = mid + 1; else hi = mid; }
        int lo2 = lo, hi2 = N_NODES;
        while (lo2 < hi2) { int mid = (lo2 + hi2) >> 1; if (batch[mid] < g + 1) lo2 = mid + 1; else hi2 = mid; }
        cntf[g] = (float)(lo2 - lo);
        return;
    }
    b -= 2;
    if (b < GZ) {
        int idx = b * 256 + t;
        *(float4*)&pooled[(size_t)idx * 4] = make_float4(0.f, 0.f, 0.f, 0.f);
        return;
    }
    b -= GZ;
    int idx = b * 256 + t;
    if (idx < 256 * 128) {               // Wt1: [256][128]
        int n = idx / 128, k = idx % 128;
        Wt1[idx] = f2b(W1[(size_t)k * 256 + n]);
    }
    int j = idx - 256 * 128;
    if (j >= 0 && j < 64 * 256) {        // Wt2: [64][256]
        int n = j / 256, k = j % 256;
        Wt2[j] = f2b(W2[(size_t)k * 64 + n]);
    }
}

// ---- scanB: exclusive scan of 391 bucket counts -> bbase, bcur ----
__global__ void scanB_k(const unsigned* __restrict__ bcnt, int* __restrict__ bbase,
                        unsigned* __restrict__ bcur) {
    __shared__ int tmp[512];
    int t = threadIdx.x;
    int v = (t < NBUK) ? (int)bcnt[t] : 0;
    tmp[t] = v;
    __syncthreads();
    for (int o = 1; o < 512; o <<= 1) {
        int u = (t >= o) ? tmp[t - o] : 0;
        __syncthreads();
        tmp[t] += u;
        __syncthreads();
    }
    if (t < NBUK) {
        int ex = tmp[t] - v;
        bbase[t] = ex;
        bcur[t] = (unsigned)ex;
    }
    if (t == NBUK - 1) bbase[NBUK] = tmp[t];
}

// ---- MEGA B: gemm1 (MFMA, hp-interleaved bf16 out) || passB (edge bucketing) ----
// h1b layout: [node][hp][c][h']  (hp = head-pair, h' = head within pair)
__global__ __launch_bounds__(256) void megaB_k(
        const float* __restrict__ X, const unsigned short* __restrict__ Wt,
        unsigned short* __restrict__ Yb,
        const float* __restrict__ asrc, const float* __restrict__ adst,
        float* __restrict__ As, float* __restrict__ Ad, int M,
        const int* __restrict__ src, const int* __restrict__ dst,
        unsigned* __restrict__ bcur, int2* __restrict__ ebuf) {
    int b = blockIdx.x;
    if (b < GB1) {
        const int lane = threadIdx.x & 63;
        const int w = threadIdx.x >> 6;
        const int r0 = b * 64 + w * 16;
        const int l15 = lane & 15;
        const int rc = min(r0 + l15, M - 1);
        const int kg = (lane >> 4) * 8;

        f32x4 acc[16] = {};
#pragma unroll
        for (int kc = 0; kc < 4; kc++) {
            int k0 = kc * 32 + kg;
            float4 xa = *(const float4*)&X[(size_t)rc * 128 + k0];
            float4 xb = *(const float4*)&X[(size_t)rc * 128 + k0 + 4];
            short8_t af;
            af[0] = f2bs(xa.x); af[1] = f2bs(xa.y); af[2] = f2bs(xa.z); af[3] = f2bs(xa.w);
            af[4] = f2bs(xb.x); af[5] = f2bs(xb.y); af[6] = f2bs(xb.z); af[7] = f2bs(xb.w);
#pragma unroll
            for (int ct = 0; ct < 16; ct++) {
                int col = ct * 16 + l15;
                short8_t bf = *(const short8_t*)&Wt[(size_t)col * 128 + k0];
                acc[ct] = __builtin_amdgcn_mfma_f32_16x16x32_bf16(af, bf, acc[ct], 0, 0, 0);
            }
        }

        const int rbase = r0 + (lane >> 4) * 4;
#pragma unroll
        for (int reg = 0; reg < 4; reg++) {
            int gr = rbase + reg;
            float s0 = 0.f, s1 = 0.f, s2 = 0.f, s3 = 0.f;
            float d0 = 0.f, d1 = 0.f, d2 = 0.f, d3 = 0.f;
#pragma unroll
            for (int cg = 0; cg < 4; cg++) {
                int c = cg * 16 + l15;
                float v0 = acc[0 * 4 + cg][reg], v1 = acc[1 * 4 + cg][reg];
                float v2 = acc[2 * 4 + cg][reg], v3 = acc[3 * 4 + cg][reg];
                s0 += v0 * asrc[0 * 64 + c]; d0 += v0 * adst[0 * 64 + c];
                s1 += v1 * asrc[1 * 64 + c]; d1 += v1 * adst[1 * 64 + c];
                s2 += v2 * asrc[2 * 64 + c]; d2 += v2 * adst[2 * 64 + c];
                s3 += v3 * asrc[3 * 64 + c]; d3 += v3 * adst[3 * 64 + c];
            }
#pragma unroll
            for (int o = 8; o > 0; o >>= 1) {
                s0 += __shfl_xor(s0, o); d0 += __shfl_xor(d0, o);
                s1 += __shfl_xor(s1, o); d1 += __shfl_xor(d1, o);
                s2 += __shfl_xor(s2, o); d2 += __shfl_xor(d2, o);
                s3 += __shfl_xor(s3, o); d3 += __shfl_xor(d3, o);
            }
            if (l15 == 0 && gr < M) {
                *(float4*)&As[gr * 4] = make_float4(s0, s1, s2, s3);
                *(float4*)&Ad[gr * 4] = make_float4(d0, d1, d2, d3);
            }
        }
#pragma unroll
        for (int reg = 0; reg < 4; reg++) {
            int gr = rbase + reg;
            if (gr >= M) continue;
#pragma unroll
            for (int cg = 0; cg < 4; cg++) {
                int c = cg * 16 + l15;
                ushort2 p0, p1;
                p0.x = f2b(acc[0 * 4 + cg][reg]);   // head 0
                p0.y = f2b(acc[1 * 4 + cg][reg]);   // head 1
                p1.x = f2b(acc[2 * 4 + cg][reg]);   // head 2
                p1.y = f2b(acc[3 * 4 + cg][reg]);   // head 3
                *(ushort2*)&Yb[(size_t)gr * 256 + c * 2] = p0;          // hp=0 half
                *(ushort2*)&Yb[(size_t)gr * 256 + 128 + c * 2] = p1;    // hp=1 half
            }
        }
        return;
    }
    b -= GB1;
    // ---------------- passB ----------------
    {
        __shared__ unsigned bins[NBUK];
        __shared__ unsigned bbl[NBUK];
        __shared__ int dstash[EPB];
        int t = threadIdx.x;
        for (int i = t; i < NBUK; i += 256) bins[i] = 0;
        __syncthreads();
        int e0 = b * EPB;
        int e1 = min(e0 + EPB, ETOT_C);
        for (int i = e0 + t; i < e1; i += 256) {
            int d = (i < N_EDGES) ? dst[i] : i - N_EDGES;
            dstash[i - e0] = d;
            atomicAdd(&bins[d >> 7], 1u);
        }
        __syncthreads();
        for (int i = t; i < NBUK; i += 256) {
            bbl[i] = bins[i] ? atomicAdd(&bcur[i], bins[i]) : 0u;
        }
        __syncthreads();
        for (int i = t; i < NBUK; i += 256) bins[i] = 0;
        __syncthreads();
        for (int i = e0 + t; i < e1; i += 256) {
            int d = dstash[i - e0];
            int s = (i < N_EDGES) ? src[i] : i - N_EDGES;
            unsigned r = atomicAdd(&bins[d >> 7], 1u);
            ebuf[bbl[d >> 7] + r] = make_int2(s, d);
        }
    }
}

// ---- passC: per-bucket CSR finalize (rowptr + csrc), no global atomics ----
__global__ __launch_bounds__(256) void passC_k(const int* __restrict__ bbase,
                                               const int2* __restrict__ ebuf,
                                               int* __restrict__ rowptr,
                                               int* __restrict__ csrc) {
    __shared__ int cnt[NPB];
    __shared__ int loc[NPB];
    __shared__ int cur[NPB];
    int b = blockIdx.x;
    int t = threadIdx.x;
    int base = bbase[b], end = bbase[b + 1];
    if (t < NPB) cnt[t] = 0;
    __syncthreads();
    for (int j = base + t; j < end; j += 256) {
        int2 e = ebuf[j];
        atomicAdd(&cnt[e.y & (NPB - 1)], 1);
    }
    __syncthreads();
    if (t < NPB) loc[t] = cnt[t];
    __syncthreads();
    for (int o = 1; o < NPB; o <<= 1) {
        int v = (t < NPB && t >= o) ? loc[t - o] : 0;
        __syncthreads();
        if (t < NPB) loc[t] += v;
        __syncthreads();
    }
    if (t < NPB) {
        int node = b * NPB + t;
        if (node < N_NODES) rowptr[node] = base + loc[t] - cnt[t];
        cur[t] = 0;
    }
    if (b == NBUK - 1 && t == 0) rowptr[N_NODES] = end;
    __syncthreads();
    for (int j = base + t; j < end; j += 256) {
        int2 e = ebuf[j];
        int n = e.y & (NPB - 1);
        int r = atomicAdd(&cur[n], 1);
        csrc[base + loc[n] - cnt[n] + r] = e.x;
    }
}

// ---- layer-2 MFMA GEMM + attn coeffs + bf16 out ----
__global__ __launch_bounds__(256) void mfma_gemm2_k(
        const unsigned short* __restrict__ Xb, const unsigned short* __restrict__ Wt,
        unsigned short* __restrict__ Yb,
        const float* __restrict__ asrc, const float* __restrict__ adst,
        float* __restrict__ As, float* __restrict__ Ad, int M) {
    const int lane = threadIdx.x & 63;
    const int w = threadIdx.x >> 6;
    const int r0 = blockIdx.x * 64 + w * 16;
    const int l15 = lane & 15;
    const int rc = min(r0 + l15, M - 1);
    const int kg = (lane >> 4) * 8;

    f32x4 acc[4] = {};
#pragma unroll
    for (int kc = 0; kc < 8; kc++) {
        int k0 = kc * 32 + kg;
        short8_t af = *(const short8_t*)&Xb[(size_t)rc * 256 + k0];
#pragma unroll
        for (int ct = 0; ct < 4; ct++) {
            int col = ct * 16 + l15;
            short8_t bf = *(const short8_t*)&Wt[(size_t)col * 256 + k0];
            acc[ct] = __builtin_amdgcn_mfma_f32_16x16x32_bf16(af, bf, acc[ct], 0, 0, 0);
        }
    }

    const int rbase = r0 + (lane >> 4) * 4;
#pragma unroll
    for (int reg = 0; reg < 4; reg++) {
        int gr = rbase + reg;
        float sv = 0.f, dv = 0.f;
#pragma unroll
        for (int ct = 0; ct < 4; ct++) {
            int c = ct * 16 + l15;
            float v = acc[ct][reg];
            sv += v * asrc[c];
            dv += v * adst[c];
        }
#pragma unroll
        for (int o = 8; o > 0; o >>= 1) { sv += __shfl_xor(sv, o); dv += __shfl_xor(dv, o); }
        if (l15 == 0 && gr < M) { As[gr] = sv; Ad[gr] = dv; }
        if (gr < M) {
#pragma unroll
            for (int ct = 0; ct < 4; ct++)
                Yb[(size_t)gr * 64 + ct * 16 + l15] = f2b(acc[ct][reg]);
        }
    }
}

// ---- layer-1 aggregate, head-pair split: one wave per (node, hp) ----
// blocks [0,HPB) -> hp=0, [HPB,2*HPB) -> hp=1 (phase-ordered dispatch ->
// each phase's gather working set is one 12.8 MB table half)
__global__ void agg1_k(const int* __restrict__ rowptr, const int* __restrict__ csrc,
                       const float* __restrict__ As, const float* __restrict__ Ad,
                       const __hip_bfloat16* __restrict__ Hb,
                       const float* __restrict__ bias,
                       unsigned short* __restrict__ Outb, int nnodes) {
    __shared__ int ssh[4][64];
    __shared__ float2 wsh[4][64];
    int lane = threadIdx.x & 63;
    int w = threadIdx.x >> 6;
    int b = blockIdx.x;
    int hp = b / HPB;
    int node = (b % HPB) * 4 + w;
    int beg = rowptr[node], end = rowptr[node + 1];
    int deg = end - beg;
    const unsigned short* hb = (const unsigned short*)Hb;
    float2 bv = *(const float2*)&Ad[node * 4 + hp * 2];
    bool fast = (deg <= 64);
    if (fast) {
        bool act = lane < deg;
        int s = act ? csrc[beg + lane] : 0;
        float2 a = *(const float2*)&As[s * 4 + hp * 2];
        float e0 = lrelu(a.x + bv.x), e1 = lrelu(a.y + bv.y);
        if (!act) { e0 = e1 = -INFINITY; }
        float m0 = e0, m1 = e1;
#pragma unroll
        for (int o = 32; o > 0; o >>= 1) {
            m0 = fmaxf(m0, __shfl_xor(m0, o)); m1 = fmaxf(m1, __shfl_xor(m1, o));
        }
        float x0 = act ? __expf(e0 - m0) : 0.f;
        float x1 = act ? __expf(e1 - m1) : 0.f;
        float d0 = x0, d1 = x1;
#pragma unroll
        for (int o = 32; o > 0; o >>= 1) {
            d0 += __shfl_xor(d0, o); d1 += __shfl_xor(d1, o);
        }
        ssh[w][lane] = s;
        wsh[w][lane] = make_float2(x0 / d0, x1 / d1);
    }
    __syncthreads();
    float acc0 = 0.f, acc1 = 0.f;
    if (fast) {
        float p0 = 0.f, p1 = 0.f;
        int j = 0;
        for (; j + 4 <= deg; j += 4) {
            int sA = ssh[w][j], sB = ssh[w][j + 1], sC = ssh[w][j + 2], sD = ssh[w][j + 3];
            float2 wA = wsh[w][j], wB = wsh[w][j + 1], wC = wsh[w][j + 2], wD = wsh[w][j + 3];
            ushort2 vA = *(const ushort2*)&hb[(size_t)sA * 256 + hp * 128 + lane * 2];
            ushort2 vB = *(const ushort2*)&hb[(size_t)sB * 256 + hp * 128 + lane * 2];
            ushort2 vC = *(const ushort2*)&hb[(size_t)sC * 256 + hp * 128 + lane * 2];
            ushort2 vD = *(const ushort2*)&hb[(size_t)sD * 256 + hp * 128 + lane * 2];
            acc0 += wA.x * b2f(vA.x) + wC.x * b2f(vC.x);
            p0   += wB.x * b2f(vB.x) + wD.x * b2f(vD.x);
            acc1 += wA.y * b2f(vA.y) + wC.y * b2f(vC.y);
            p1   += wB.y * b2f(vB.y) + wD.y * b2f(vD.y);
        }
        for (; j < deg; j++) {
            int s = ssh[w][j];
            float2 wt = wsh[w][j];
            ushort2 v = *(const ushort2*)&hb[(size_t)s * 256 + hp * 128 + lane * 2];
            acc0 += wt.x * b2f(v.x); acc1 += wt.y * b2f(v.y);
        }
        acc0 += p0; acc1 += p1;
    } else {
        float m0 = -INFINITY, m1 = -INFINITY;
        for (int j = beg + lane; j < end; j += 64) {
            float2 a = *(const float2*)&As[csrc[j] * 4 + hp * 2];
            m0 = fmaxf(m0, lrelu(a.x + bv.x)); m1 = fmaxf(m1, lrelu(a.y + bv.y));
        }
#pragma unroll
        for (int o = 32; o > 0; o >>= 1) {
            m0 = fmaxf(m0, __shfl_xor(m0, o)); m1 = fmaxf(m1, __shfl_xor(m1, o));
        }
        float d0 = 0.f, d1 = 0.f;
        for (int j = beg + lane; j < end; j += 64) {
            float2 a = *(const float2*)&As[csrc[j] * 4 + hp * 2];
            d0 += __expf(lrelu(a.x + bv.x) - m0); d1 += __expf(lrelu(a.y + bv.y) - m1);
        }
#pragma unroll
        for (int o = 32; o > 0; o >>= 1) {
            d0 += __shfl_xor(d0, o); d1 += __shfl_xor(d1, o);
        }
        for (int j = beg; j < end; j++) {
            int s = csrc[j];
            float2 a = *(const float2*)&As[s * 4 + hp * 2];
            float w0 = __expf(lrelu(a.x + bv.x) - m0) / d0;
            float w1 = __expf(lrelu(a.y + bv.y) - m1) / d1;
            ushort2 v = *(const ushort2*)&hb[(size_t)s * 256 + hp * 128 + lane * 2];
            acc0 += w0 * b2f(v.x); acc1 += w1 * b2f(v.y);
        }
    }
    int h0 = hp * 2;
    float r0 = acc0 + bias[h0 * 64 + lane];
    float r1 = acc1 + bias[(h0 + 1) * 64 + lane];
    r0 = r0 > 0.f ? r0 : expm1f(r0);
    r1 = r1 > 0.f ? r1 : expm1f(r1);
    size_t base = (size_t)node * 256;
    Outb[base + h0 * 64 + lane] = f2b(r0);
    Outb[base + (h0 + 1) * 64 + lane] = f2b(r1);
}

// ---- layer-2 fused softmax + gather + bias + ELU + mean-pool accum (H=1) ----
__global__ void agg2_k(const int* __restrict__ rowptr, const int* __restrict__ csrc,
                       const float* __restrict__ As, const float* __restrict__ Ad,
                       const __hip_bfloat16* __restrict__ Hb,
                       const float* __restrict__ bias, const int* __restrict__ batch,
                       float* __restrict__ pooled, int nnodes) {
    __shared__ int ssh[4][64];
    __shared__ float wsh[4][64];
    int lane = threadIdx.x & 63;
    int w = threadIdx.x >> 6;
    int node = blockIdx.x * 4 + w;
    int beg = rowptr[node], end = rowptr[node + 1];
    int deg = end - beg;
    const unsigned short* hb = (const unsigned short*)Hb;
    float ad = Ad[node];
    bool fast = (deg <= 64);
    if (fast) {
        bool act = lane < deg;
        int s = act ? csrc[beg + lane] : 0;
        float e = lrelu(As[s] + ad);
        if (!act) e = -INFINITY;
        float m = e;
#pragma unroll
        for (int o = 32; o > 0; o >>= 1) m = fmaxf(m, __shfl_xor(m, o));
        float x = act ? __expf(e - m) : 0.f;
        float d = x;
#pragma unroll
        for (int o = 32; o > 0; o >>= 1) d += __shfl_xor(d, o);
        ssh[w][lane] = s;
        wsh[w][lane] = x / d;
    }
    __syncthreads();
    float acc = 0.f;
    if (fast) {
        float p = 0.f;
        int j = 0;
        for (; j + 4 <= deg; j += 4) {
            int sA = ssh[w][j], sB = ssh[w][j + 1], sC = ssh[w][j + 2], sD = ssh[w][j + 3];
            float wA = wsh[w][j], wB = wsh[w][j + 1], wC = wsh[w][j + 2], wD = wsh[w][j + 3];
            acc += wA * b2f(hb[(size_t)sA * 64 + lane]) + wC * b2f(hb[(size_t)sC * 64 + lane]);
            p   += wB * b2f(hb[(size_t)sB * 64 + lane]) + wD * b2f(hb[(size_t)sD * 64 + lane]);
        }
        for (; j < deg; j++) acc += wsh[w][j] * b2f(hb[(size_t)ssh[w][j] * 64 + lane]);
        acc += p;
    } else {
        float m = -INFINITY;
        for (int j = beg + lane; j < end; j += 64) m = fmaxf(m, lrelu(As[csrc[j]] + ad));
#pragma unroll
        for (int o = 32; o > 0; o >>= 1) m = fmaxf(m, __shfl_xor(m, o));
        float d = 0.f;
        for (int j = beg + lane; j < end; j += 64) d += __expf(lrelu(As[csrc[j]] + ad) - m);
#pragma unroll
        for (int o = 32; o > 0; o >>= 1) d += __shfl_xor(d, o);
        for (int j = beg; j < end; j++) {
            int s = csrc[j];
            float wt = __expf(lrelu(As[s] + ad) - m) / d;
            acc += wt * b2f(hb[(size_t)s * 64 + lane]);
        }
    }
    float v = acc + bias[lane];
    v = v > 0.f ? v : expm1f(v);
    atomicAdd(&pooled[batch[node] * 64 + lane], v);
}

// ---- final: out[g,:] = (pooled[g,:]/cnt) @ Wl + bl ----
__global__ void final_k(const float* __restrict__ pooled, const float* __restrict__ cnt,
                        const float* __restrict__ Wl, const float* __restrict__ bl,
                        float* __restrict__ out) {
    int g = blockIdx.x;
    int t = threadIdx.x;  // 64
    __shared__ float s[64];
    float c = cnt[g];
    c = c > 1.f ? c : 1.f;
    s[t] = pooled[g * 64 + t] / c;
    __syncthreads();
    if (t < OUT_CH) {
        float acc = bl[t];
        for (int k = 0; k < 64; k++) acc += s[k] * Wl[k * OUT_CH + t];
        out[g * OUT_CH + t] = acc;
    }
}

extern "C" void kernel_launch(void* const* d_in, const int* in_sizes, int n_in,
                              void* d_out, int out_size, void* d_ws, size_t ws_size,
                              hipStream_t stream) {
    const float* x    = (const float*)d_in[0];
    const int*   ei   = (const int*)d_in[1];
    const int*   batch= (const int*)d_in[2];
    const float* W1   = (const float*)d_in[3];
    const float* as1  = (const float*)d_in[4];
    const float* ad1  = (const float*)d_in[5];
    const float* b1   = (const float*)d_in[6];
    const float* W2   = (const float*)d_in[7];
    const float* as2  = (const float*)d_in[8];
    const float* ad2  = (const float*)d_in[9];
    const float* b2   = (const float*)d_in[10];
    const float* Wl   = (const float*)d_in[11];
    const float* bl   = (const float*)d_in[12];
    float* out = (float*)d_out;

    const int* src = ei;
    const int* dst = ei + N_EDGES;

    char* ws = (char*)d_ws;
    size_t off = 0;
    auto alloc = [&](size_t bytes) {
        void* p = ws + off;
        off = (off + bytes + 255) & ~((size_t)255);
        return p;
    };
    unsigned short* h1b  = (unsigned short*)alloc((size_t)N_NODES * 256 * 2);
    unsigned short* out1b= (unsigned short*)alloc((size_t)N_NODES * 256 * 2);
    float* As1    = (float*)alloc((size_t)N_NODES * 4 * 4);
    float* Ad1    = (float*)alloc((size_t)N_NODES * 4 * 4);
    float* As2    = (float*)alloc((size_t)N_NODES * 4);
    float* Ad2    = (float*)alloc((size_t)N_NODES * 4);
    int*   rowptr = (int*)  alloc((size_t)(N_NODES + 1) * 4);
    int*   csrc   = (int*)  alloc((size_t)ETOT_C * 4);
    int2*  ebuf   = (int2*) alloc((size_t)ETOT_C * 8);
    unsigned* bcnt= (unsigned*)alloc((size_t)NBUK * 4);
    int*   bbase  = (int*)  alloc((size_t)(NBUK + 1) * 4);
    unsigned* bcur= (unsigned*)alloc((size_t)NBUK * 4);
    unsigned short* Wt1 = (unsigned short*)alloc((size_t)256 * 128 * 2);
    unsigned short* Wt2 = (unsigned short*)alloc((size_t)64 * 256 * 2);
    float* pooled = (float*)alloc((size_t)N_GRAPHS * 64 * 4);
    float* cntf   = (float*)alloc((size_t)N_GRAPHS * 4);
    unsigned short* h2b = h1b;   // aliases h1b (dead after agg1_k)

    hipMemsetAsync(bcnt, 0, (size_t)NBUK * 4, stream);

    // ---- megaA: passA || cntg || pooled-zero || convw ----
    megaA_k<<<GA + 2 + GZ + GW, 256, 0, stream>>>(dst, bcnt, batch, cntf, pooled,
                                                  W1, W2, Wt1, Wt2);
    scanB_k<<<1, 512, 0, stream>>>(bcnt, bbase, bcur);

    // ---- megaB: gemm1 || passB ----
    megaB_k<<<GB1 + GA, 256, 0, stream>>>(x, Wt1, h1b, as1, ad1, As1, Ad1, N_NODES,
                                          src, dst, bcur, ebuf);
    passC_k<<<NBUK, 256, 0, stream>>>(bbase, ebuf, rowptr, csrc);

    // ---- layer 1 aggregate (head-pair-phased) ----
    agg1_k<<<2 * HPB, 256, 0, stream>>>(rowptr, csrc, As1, Ad1,
                                        (const __hip_bfloat16*)h1b, b1, out1b, N_NODES);

    // ---- layer 2 ----
    mfma_gemm2_k<<<(N_NODES + 63) / 64, 256, 0, stream>>>(out1b, Wt2, h2b, as2, ad2,
                                                          As2, Ad2, N_NODES);
    agg2_k<<<N_NODES / 4, 256, 0, stream>>>(rowptr, csrc, As2, Ad2,
                                            (const __hip_bfloat16*)h2b, b2, batch, pooled, N_NODES);

    // ---- head ----
    final_k<<<N_GRAPHS, 64, 0, stream>>>(pooled, cntf, Wl, bl, out);
}

// Round 16
// 215.474 us; speedup vs baseline: 1.0333x; 1.0333x over previous
//
#include <hip/hip_runtime.h>
#include <hip/hip_bf16.h>
#include <math.h>

#define N_NODES 50000
#define N_EDGES 800000
#define IN_CH 128
#define HID 64
#define HEADS 4
#define OUT_CH 10
#define N_GRAPHS 512
#define NEG_SLOPE 0.2f

#define ETOT_C (N_EDGES + N_NODES)          // 850000
#define NPB 128                              // nodes per bucket
#define NBUK ((N_NODES + NPB - 1) / NPB)     // 391 buckets
#define EPB 2048                             // edges per pass-A/B block
#define GA ((ETOT_C + EPB - 1) / EPB)        // 416 passA/passB blocks
#define GB1 ((N_NODES + 63) / 64)            // 782 gemm1 blocks
#define GZ 32                                // pooled-zero blocks
#define GW 192                               // convw blocks

using short8_t = __attribute__((ext_vector_type(8))) short;
using f32x4 = __attribute__((ext_vector_type(4))) float;

__device__ __forceinline__ float b2f(unsigned short u) {
    return __uint_as_float(((unsigned)u) << 16);
}
__device__ __forceinline__ unsigned short f2b(float f) {
    __hip_bfloat16 b = __float2bfloat16(f);
    return *(unsigned short*)&b;
}
__device__ __forceinline__ short f2bs(float f) {
    __hip_bfloat16 b = __float2bfloat16(f);
    return *(short*)&b;
}
__device__ __forceinline__ float lrelu(float x) { return x > 0.f ? x : NEG_SLOPE * x; }

// ---- MEGA A: passA bucket-count || cntg || pooled-zero || convw ----
__global__ __launch_bounds__(256) void megaA_k(
        const int* __restrict__ dst, unsigned* __restrict__ bcnt,
        const int* __restrict__ batch, float* __restrict__ cntf,
        float* __restrict__ pooled,
        const float* __restrict__ W1, const float* __restrict__ W2,
        unsigned short* __restrict__ Wt1, unsigned short* __restrict__ Wt2) {
    int b = blockIdx.x;
    int t = threadIdx.x;
    if (b < GA) {
        __shared__ unsigned bins[NBUK];
        for (int i = t; i < NBUK; i += 256) bins[i] = 0;
        __syncthreads();
        int e0 = b * EPB;
        int e1 = min(e0 + EPB, ETOT_C);
        for (int i = e0 + t; i < e1; i += 256) {
            int d = (i < N_EDGES) ? dst[i] : i - N_EDGES;
            atomicAdd(&bins[d >> 7], 1u);
        }
        __syncthreads();
        for (int i = t; i < NBUK; i += 256)
            if (bins[i]) atomicAdd(&bcnt[i], bins[i]);
        return;
    }
    b -= GA;
    if (b < 2) {
        int g = b * 256 + t;
        if (g >= N_GRAPHS) return;
        int lo = 0, hi = N_NODES;
        while (lo < hi) { int mid = (lo + hi) >> 1; if (batch[mid] < g) lo = mid + 1; else hi = mid; }
        int lo2 = lo, hi2 = N_NODES;
        while (lo2 < hi2) { int mid = (lo2 + hi2) >> 1; if (batch[mid] < g + 1) lo2 = mid + 1; else hi2 = mid; }
        cntf[g] = (float)(lo2 - lo);
        return;
    }
    b -= 2;
    if (b < GZ) {
        int idx = b * 256 + t;
        *(float4*)&pooled[(size_t)idx * 4] = make_float4(0.f, 0.f, 0.f, 0.f);
        return;
    }
    b -= GZ;
    int idx = b * 256 + t;
    if (idx < 256 * 128) {               // Wt1: [256][128]
        int n = idx / 128, k = idx % 128;
        Wt1[idx] = f2b(W1[(size_t)k * 256 + n]);
    }
    int j = idx - 256 * 128;
    if (j >= 0 && j < 64 * 256) {        // Wt2: [64][256]
        int n = j / 256, k = j % 256;
        Wt2[j] = f2b(W2[(size_t)k * 64 + n]);
    }
}

// ---- scanB: exclusive scan of 391 bucket counts -> bbase, bcur ----
__global__ void scanB_k(const unsigned* __restrict__ bcnt, int* __restrict__ bbase,
                        unsigned* __restrict__ bcur) {
    __shared__ int tmp[512];
    int t = threadIdx.x;
    int v = (t < NBUK) ? (int)bcnt[t] : 0;
    tmp[t] = v;
    __syncthreads();
    for (int o = 1; o < 512; o <<= 1) {
        int u = (t >= o) ? tmp[t - o] : 0;
        __syncthreads();
        tmp[t] += u;
        __syncthreads();
    }
    if (t < NBUK) {
        int ex = tmp[t] - v;
        bbase[t] = ex;
        bcur[t] = (unsigned)ex;
    }
    if (t == NBUK - 1) bbase[NBUK] = tmp[t];
}

// ---- MEGA B: gemm1 (MFMA) || passB (edge bucketing) ----
__global__ __launch_bounds__(256) void megaB_k(
        const float* __restrict__ X, const unsigned short* __restrict__ Wt,
        unsigned short* __restrict__ Yb,
        const float* __restrict__ asrc, const float* __restrict__ adst,
        float* __restrict__ As, float* __restrict__ Ad, int M,
        const int* __restrict__ src, const int* __restrict__ dst,
        unsigned* __restrict__ bcur, int2* __restrict__ ebuf) {
    int b = blockIdx.x;
    if (b < GB1) {
        const int lane = threadIdx.x & 63;
        const int w = threadIdx.x >> 6;
        const int r0 = b * 64 + w * 16;
        const int l15 = lane & 15;
        const int rc = min(r0 + l15, M - 1);
        const int kg = (lane >> 4) * 8;

        f32x4 acc[16] = {};
#pragma unroll
        for (int kc = 0; kc < 4; kc++) {
            int k0 = kc * 32 + kg;
            float4 xa = *(const float4*)&X[(size_t)rc * 128 + k0];
            float4 xb = *(const float4*)&X[(size_t)rc * 128 + k0 + 4];
            short8_t af;
            af[0] = f2bs(xa.x); af[1] = f2bs(xa.y); af[2] = f2bs(xa.z); af[3] = f2bs(xa.w);
            af[4] = f2bs(xb.x); af[5] = f2bs(xb.y); af[6] = f2bs(xb.z); af[7] = f2bs(xb.w);
#pragma unroll
            for (int ct = 0; ct < 16; ct++) {
                int col = ct * 16 + l15;
                short8_t bf = *(const short8_t*)&Wt[(size_t)col * 128 + k0];
                acc[ct] = __builtin_amdgcn_mfma_f32_16x16x32_bf16(af, bf, acc[ct], 0, 0, 0);
            }
        }

        const int rbase = r0 + (lane >> 4) * 4;
#pragma unroll
        for (int reg = 0; reg < 4; reg++) {
            int gr = rbase + reg;
            float s0 = 0.f, s1 = 0.f, s2 = 0.f, s3 = 0.f;
            float d0 = 0.f, d1 = 0.f, d2 = 0.f, d3 = 0.f;
#pragma unroll
            for (int cg = 0; cg < 4; cg++) {
                int c = cg * 16 + l15;
                float v0 = acc[0 * 4 + cg][reg], v1 = acc[1 * 4 + cg][reg];
                float v2 = acc[2 * 4 + cg][reg], v3 = acc[3 * 4 + cg][reg];
                s0 += v0 * asrc[0 * 64 + c]; d0 += v0 * adst[0 * 64 + c];
                s1 += v1 * asrc[1 * 64 + c]; d1 += v1 * adst[1 * 64 + c];
                s2 += v2 * asrc[2 * 64 + c]; d2 += v2 * adst[2 * 64 + c];
                s3 += v3 * asrc[3 * 64 + c]; d3 += v3 * adst[3 * 64 + c];
            }
#pragma unroll
            for (int o = 8; o > 0; o >>= 1) {
                s0 += __shfl_xor(s0, o); d0 += __shfl_xor(d0, o);
                s1 += __shfl_xor(s1, o); d1 += __shfl_xor(d1, o);
                s2 += __shfl_xor(s2, o); d2 += __shfl_xor(d2, o);
                s3 += __shfl_xor(s3, o); d3 += __shfl_xor(d3, o);
            }
            if (l15 == 0 && gr < M) {
                *(float4*)&As[gr * 4] = make_float4(s0, s1, s2, s3);
                *(float4*)&Ad[gr * 4] = make_float4(d0, d1, d2, d3);
            }
        }
#pragma unroll
        for (int reg = 0; reg < 4; reg++) {
            int gr = rbase + reg;
            if (gr >= M) continue;
#pragma unroll
            for (int cg = 0; cg < 4; cg++) {
                int c = cg * 16 + l15;
                ushort4 p;
                p.x = f2b(acc[0 * 4 + cg][reg]);
                p.y = f2b(acc[1 * 4 + cg][reg]);
                p.z = f2b(acc[2 * 4 + cg][reg]);
                p.w = f2b(acc[3 * 4 + cg][reg]);
                *(ushort4*)&Yb[(size_t)gr * 256 + c * 4] = p;
            }
        }
        return;
    }
    b -= GB1;
    // ---------------- passB ----------------
    {
        __shared__ unsigned bins[NBUK];
        __shared__ unsigned bbl[NBUK];
        __shared__ int dstash[EPB];
        int t = threadIdx.x;
        for (int i = t; i < NBUK; i += 256) bins[i] = 0;
        __syncthreads();
        int e0 = b * EPB;
        int e1 = min(e0 + EPB, ETOT_C);
        for (int i = e0 + t; i < e1; i += 256) {
            int d = (i < N_EDGES) ? dst[i] : i - N_EDGES;
            dstash[i - e0] = d;
            atomicAdd(&bins[d >> 7], 1u);
        }
        __syncthreads();
        for (int i = t; i < NBUK; i += 256) {
            bbl[i] = bins[i] ? atomicAdd(&bcur[i], bins[i]) : 0u;
        }
        __syncthreads();
        for (int i = t; i < NBUK; i += 256) bins[i] = 0;
        __syncthreads();
        for (int i = e0 + t; i < e1; i += 256) {
            int d = dstash[i - e0];
            int s = (i < N_EDGES) ? src[i] : i - N_EDGES;
            unsigned r = atomicAdd(&bins[d >> 7], 1u);
            ebuf[bbl[d >> 7] + r] = make_int2(s, d);
        }
    }
}

// ---- passC: per-bucket CSR finalize (rowptr + csrc), no global atomics ----
__global__ __launch_bounds__(256) void passC_k(const int* __restrict__ bbase,
                                               const int2* __restrict__ ebuf,
                                               int* __restrict__ rowptr,
                                               int* __restrict__ csrc) {
    __shared__ int cnt[NPB];
    __shared__ int loc[NPB];
    __shared__ int cur[NPB];
    int b = blockIdx.x;
    int t = threadIdx.x;
    int base = bbase[b], end = bbase[b + 1];
    if (t < NPB) cnt[t] = 0;
    __syncthreads();
    for (int j = base + t; j < end; j += 256) {
        int2 e = ebuf[j];
        atomicAdd(&cnt[e.y & (NPB - 1)], 1);
    }
    __syncthreads();
    if (t < NPB) loc[t] = cnt[t];
    __syncthreads();
    for (int o = 1; o < NPB; o <<= 1) {
        int v = (t < NPB && t >= o) ? loc[t - o] : 0;
        __syncthreads();
        if (t < NPB) loc[t] += v;
        __syncthreads();
    }
    if (t < NPB) {
        int node = b * NPB + t;
        if (node < N_NODES) rowptr[node] = base + loc[t] - cnt[t];
        cur[t] = 0;
    }
    if (b == NBUK - 1 && t == 0) rowptr[N_NODES] = end;
    __syncthreads();
    for (int j = base + t; j < end; j += 256) {
        int2 e = ebuf[j];
        int n = e.y & (NPB - 1);
        int r = atomicAdd(&cur[n], 1);
        csrc[base + loc[n] - cnt[n] + r] = e.x;
    }
}

// ---- layer-2 MFMA GEMM + attn coeffs + bf16 out ----
__global__ __launch_bounds__(256) void mfma_gemm2_k(
        const unsigned short* __restrict__ Xb, const unsigned short* __restrict__ Wt,
        unsigned short* __restrict__ Yb,
        const float* __restrict__ asrc, const float* __restrict__ adst,
        float* __restrict__ As, float* __restrict__ Ad, int M) {
    const int lane = threadIdx.x & 63;
    const int w = threadIdx.x >> 6;
    const int r0 = blockIdx.x * 64 + w * 16;
    const int l15 = lane & 15;
    const int rc = min(r0 + l15, M - 1);
    const int kg = (lane >> 4) * 8;

    f32x4 acc[4] = {};
#pragma unroll
    for (int kc = 0; kc < 8; kc++) {
        int k0 = kc * 32 + kg;
        short8_t af = *(const short8_t*)&Xb[(size_t)rc * 256 + k0];
#pragma unroll
        for (int ct = 0; ct < 4; ct++) {
            int col = ct * 16 + l15;
            short8_t bf = *(const short8_t*)&Wt[(size_t)col * 256 + k0];
            acc[ct] = __builtin_amdgcn_mfma_f32_16x16x32_bf16(af, bf, acc[ct], 0, 0, 0);
        }
    }

    const int rbase = r0 + (lane >> 4) * 4;
#pragma unroll
    for (int reg = 0; reg < 4; reg++) {
        int gr = rbase + reg;
        float sv = 0.f, dv = 0.f;
#pragma unroll
        for (int ct = 0; ct < 4; ct++) {
            int c = ct * 16 + l15;
            float v = acc[ct][reg];
            sv += v * asrc[c];
            dv += v * adst[c];
        }
#pragma unroll
        for (int o = 8; o > 0; o >>= 1) { sv += __shfl_xor(sv, o); dv += __shfl_xor(dv, o); }
        if (l15 == 0 && gr < M) { As[gr] = sv; Ad[gr] = dv; }
        if (gr < M) {
#pragma unroll
            for (int ct = 0; ct < 4; ct++)
                Yb[(size_t)gr * 64 + ct * 16 + l15] = f2b(acc[ct][reg]);
        }
    }
}

// ---- layer-1 fused softmax + gather + bias + ELU (H=4), bf16 output ----
__global__ void agg1_k(const int* __restrict__ rowptr, const int* __restrict__ csrc,
                       const float* __restrict__ As, const float* __restrict__ Ad,
                       const __hip_bfloat16* __restrict__ Hb,
                       const float* __restrict__ bias,
                       unsigned short* __restrict__ Outb, int nnodes) {
    __shared__ int ssh[4][64];
    __shared__ float4 wsh[4][64];
    int lane = threadIdx.x & 63;
    int w = threadIdx.x >> 6;
    int node = blockIdx.x * 4 + w;
    int beg = rowptr[node], end = rowptr[node + 1];
    int deg = end - beg;
    const unsigned short* hb = (const unsigned short*)Hb;
    float4 bv = *(const float4*)&Ad[node * 4];
    bool fast = (deg <= 64);
    if (fast) {
        bool act = lane < deg;
        int s = act ? csrc[beg + lane] : 0;
        float4 a = *(const float4*)&As[s * 4];
        float e0 = lrelu(a.x + bv.x), e1 = lrelu(a.y + bv.y);
        float e2 = lrelu(a.z + bv.z), e3 = lrelu(a.w + bv.w);
        if (!act) { e0 = e1 = e2 = e3 = -INFINITY; }
        float m0 = e0, m1 = e1, m2 = e2, m3 = e3;
#pragma unroll
        for (int o = 32; o > 0; o >>= 1) {
            m0 = fmaxf(m0, __shfl_xor(m0, o)); m1 = fmaxf(m1, __shfl_xor(m1, o));
            m2 = fmaxf(m2, __shfl_xor(m2, o)); m3 = fmaxf(m3, __shfl_xor(m3, o));
        }
        float x0 = act ? __expf(e0 - m0) : 0.f;
        float x1 = act ? __expf(e1 - m1) : 0.f;
        float x2 = act ? __expf(e2 - m2) : 0.f;
        float x3 = act ? __expf(e3 - m3) : 0.f;
        float d0 = x0, d1 = x1, d2 = x2, d3 = x3;
#pragma unroll
        for (int o = 32; o > 0; o >>= 1) {
            d0 += __shfl_xor(d0, o); d1 += __shfl_xor(d1, o);
            d2 += __shfl_xor(d2, o); d3 += __shfl_xor(d3, o);
        }
        ssh[w][lane] = s;
        wsh[w][lane] = make_float4(x0 / d0, x1 / d1, x2 / d2, x3 / d3);
    }
    __syncthreads();
    float acc0 = 0.f, acc1 = 0.f, acc2 = 0.f, acc3 = 0.f;
    if (fast) {
        float p0 = 0.f, p1 = 0.f, p2 = 0.f, p3 = 0.f;
        int j = 0;
        for (; j + 4 <= deg; j += 4) {
            int sA = ssh[w][j], sB = ssh[w][j + 1], sC = ssh[w][j + 2], sD = ssh[w][j + 3];
            float4 wA = wsh[w][j], wB = wsh[w][j + 1], wC = wsh[w][j + 2], wD = wsh[w][j + 3];
            ushort4 vA = *(const ushort4*)&hb[(size_t)sA * 256 + lane * 4];
            ushort4 vB = *(const ushort4*)&hb[(size_t)sB * 256 + lane * 4];
            ushort4 vC = *(const ushort4*)&hb[(size_t)sC * 256 + lane * 4];
            ushort4 vD = *(const ushort4*)&hb[(size_t)sD * 256 + lane * 4];
            acc0 += wA.x * b2f(vA.x) + wC.x * b2f(vC.x);
            p0   += wB.x * b2f(vB.x) + wD.x * b2f(vD.x);
            acc1 += wA.y * b2f(vA.y) + wC.y * b2f(vC.y);
            p1   += wB.y * b2f(vB.y) + wD.y * b2f(vD.y);
            acc2 += wA.z * b2f(vA.z) + wC.z * b2f(vC.z);
            p2   += wB.z * b2f(vB.z) + wD.z * b2f(vD.z);
            acc3 += wA.w * b2f(vA.w) + wC.w * b2f(vC.w);
            p3   += wB.w * b2f(vB.w) + wD.w * b2f(vD.w);
        }
        for (; j < deg; j++) {
            int s = ssh[w][j];
            float4 wt = wsh[w][j];
            ushort4 v = *(const ushort4*)&hb[(size_t)s * 256 + lane * 4];
            acc0 += wt.x * b2f(v.x); acc1 += wt.y * b2f(v.y);
            acc2 += wt.z * b2f(v.z); acc3 += wt.w * b2f(v.w);
        }
        acc0 += p0; acc1 += p1; acc2 += p2; acc3 += p3;
    } else {
        float m0 = -INFINITY, m1 = -INFINITY, m2 = -INFINITY, m3 = -INFINITY;
        for (int j = beg + lane; j < end; j += 64) {
            float4 a = *(const float4*)&As[csrc[j] * 4];
            m0 = fmaxf(m0, lrelu(a.x + bv.x)); m1 = fmaxf(m1, lrelu(a.y + bv.y));
            m2 = fmaxf(m2, lrelu(a.z + bv.z)); m3 = fmaxf(m3, lrelu(a.w + bv.w));
        }
#pragma unroll
        for (int o = 32; o > 0; o >>= 1) {
            m0 = fmaxf(m0, __shfl_xor(m0, o)); m1 = fmaxf(m1, __shfl_xor(m1, o));
            m2 = fmaxf(m2, __shfl_xor(m2, o)); m3 = fmaxf(m3, __shfl_xor(m3, o));
        }
        float d0 = 0.f, d1 = 0.f, d2 = 0.f, d3 = 0.f;
        for (int j = beg + lane; j < end; j += 64) {
            float4 a = *(const float4*)&As[csrc[j] * 4];
            d0 += __expf(lrelu(a.x + bv.x) - m0); d1 += __expf(lrelu(a.y + bv.y) - m1);
            d2 += __expf(lrelu(a.z + bv.z) - m2); d3 += __expf(lrelu(a.w + bv.w) - m3);
        }
#pragma unroll
        for (int o = 32; o > 0; o >>= 1) {
            d0 += __shfl_xor(d0, o); d1 += __shfl_xor(d1, o);
            d2 += __shfl_xor(d2, o); d3 += __shfl_xor(d3, o);
        }
        for (int j = beg; j < end; j++) {
            int s = csrc[j];
            float4 a = *(const float4*)&As[s * 4];
            float w0 = __expf(lrelu(a.x + bv.x) - m0) / d0;
            float w1 = __expf(lrelu(a.y + bv.y) - m1) / d1;
            float w2 = __expf(lrelu(a.z + bv.z) - m2) / d2;
            float w3 = __expf(lrelu(a.w + bv.w) - m3) / d3;
            ushort4 v = *(const ushort4*)&hb[(size_t)s * 256 + lane * 4];
            acc0 += w0 * b2f(v.x); acc1 += w1 * b2f(v.y);
            acc2 += w2 * b2f(v.z); acc3 += w3 * b2f(v.w);
        }
    }
    float r0 = acc0 + bias[0 * 64 + lane];
    float r1 = acc1 + bias[1 * 64 + lane];
    float r2 = acc2 + bias[2 * 64 + lane];
    float r3 = acc3 + bias[3 * 64 + lane];
    r0 = r0 > 0.f ? r0 : expm1f(r0);
    r1 = r1 > 0.f ? r1 : expm1f(r1);
    r2 = r2 > 0.f ? r2 : expm1f(r2);
    r3 = r3 > 0.f ? r3 : expm1f(r3);
    size_t base = (size_t)node * 256;
    Outb[base + 0 * 64 + lane] = f2b(r0);
    Outb[base + 1 * 64 + lane] = f2b(r1);
    Outb[base + 2 * 64 + lane] = f2b(r2);
    Outb[base + 3 * 64 + lane] = f2b(r3);
}

// ---- layer-2 fused softmax + gather + bias + ELU + mean-pool accum (H=1) ----
__global__ void agg2_k(const int* __restrict__ rowptr, const int* __restrict__ csrc,
                       const float* __restrict__ As, const float* __restrict__ Ad,
                       const __hip_bfloat16* __restrict__ Hb,
                       const float* __restrict__ bias, const int* __restrict__ batch,
                       float* __restrict__ pooled, int nnodes) {
    __shared__ int ssh[4][64];
    __shared__ float wsh[4][64];
    int lane = threadIdx.x & 63;
    int w = threadIdx.x >> 6;
    int node = blockIdx.x * 4 + w;
    int beg = rowptr[node], end = rowptr[node + 1];
    int deg = end - beg;
    const unsigned short* hb = (const unsigned short*)Hb;
    float ad = Ad[node];
    bool fast = (deg <= 64);
    if (fast) {
        bool act = lane < deg;
        int s = act ? csrc[beg + lane] : 0;
        float e = lrelu(As[s] + ad);
        if (!act) e = -INFINITY;
        float m = e;
#pragma unroll
        for (int o = 32; o > 0; o >>= 1) m = fmaxf(m, __shfl_xor(m, o));
        float x = act ? __expf(e - m) : 0.f;
        float d = x;
#pragma unroll
        for (int o = 32; o > 0; o >>= 1) d += __shfl_xor(d, o);
        ssh[w][lane] = s;
        wsh[w][lane] = x / d;
    }
    __syncthreads();
    float acc = 0.f;
    if (fast) {
        float p = 0.f;
        int j = 0;
        for (; j + 4 <= deg; j += 4) {
            int sA = ssh[w][j], sB = ssh[w][j + 1], sC = ssh[w][j + 2], sD = ssh[w][j + 3];
            float wA = wsh[w][j], wB = wsh[w][j + 1], wC = wsh[w][j + 2], wD = wsh[w][j + 3];
            acc += wA * b2f(hb[(size_t)sA * 64 + lane]) + wC * b2f(hb[(size_t)sC * 64 + lane]);
            p   += wB * b2f(hb[(size_t)sB * 64 + lane]) + wD * b2f(hb[(size_t)sD * 64 + lane]);
        }
        for (; j < deg; j++) acc += wsh[w][j] * b2f(hb[(size_t)ssh[w][j] * 64 + lane]);
        acc += p;
    } else {
        float m = -INFINITY;
        for (int j = beg + lane; j < end; j += 64) m = fmaxf(m, lrelu(As[csrc[j]] + ad));
#pragma unroll
        for (int o = 32; o > 0; o >>= 1) m = fmaxf(m, __shfl_xor(m, o));
        float d = 0.f;
        for (int j = beg + lane; j < end; j += 64) d += __expf(lrelu(As[csrc[j]] + ad) - m);
#pragma unroll
        for (int o = 32; o > 0; o >>= 1) d += __shfl_xor(d, o);
        for (int j = beg; j < end; j++) {
            int s = csrc[j];
            float wt = __expf(lrelu(As[s] + ad) - m) / d;
            acc += wt * b2f(hb[(size_t)s * 64 + lane]);
        }
    }
    float v = acc + bias[lane];
    v = v > 0.f ? v : expm1f(v);
    atomicAdd(&pooled[batch[node] * 64 + lane], v);
}

// ---- final: out[g,:] = (pooled[g,:]/cnt) @ Wl + bl ----
__global__ void final_k(const float* __restrict__ pooled, const float* __restrict__ cnt,
                        const float* __restrict__ Wl, const float* __restrict__ bl,
                        float* __restrict__ out) {
    int g = blockIdx.x;
    int t = threadIdx.x;  // 64
    __shared__ float s[64];
    float c = cnt[g];
    c = c > 1.f ? c : 1.f;
    s[t] = pooled[g * 64 + t] / c;
    __syncthreads();
    if (t < OUT_CH) {
        float acc = bl[t];
        for (int k = 0; k < 64; k++) acc += s[k] * Wl[k * OUT_CH + t];
        out[g * OUT_CH + t] = acc;
    }
}

extern "C" void kernel_launch(void* const* d_in, const int* in_sizes, int n_in,
                              void* d_out, int out_size, void* d_ws, size_t ws_size,
                              hipStream_t stream) {
    const float* x    = (const float*)d_in[0];
    const int*   ei   = (const int*)d_in[1];
    const int*   batch= (const int*)d_in[2];
    const float* W1   = (const float*)d_in[3];
    const float* as1  = (const float*)d_in[4];
    const float* ad1  = (const float*)d_in[5];
    const float* b1   = (const float*)d_in[6];
    const float* W2   = (const float*)d_in[7];
    const float* as2  = (const float*)d_in[8];
    const float* ad2  = (const float*)d_in[9];
    const float* b2   = (const float*)d_in[10];
    const float* Wl   = (const float*)d_in[11];
    const float* bl   = (const float*)d_in[12];
    float* out = (float*)d_out;

    const int* src = ei;
    const int* dst = ei + N_EDGES;

    char* ws = (char*)d_ws;
    size_t off = 0;
    auto alloc = [&](size_t bytes) {
        void* p = ws + off;
        off = (off + bytes + 255) & ~((size_t)255);
        return p;
    };
    unsigned short* h1b  = (unsigned short*)alloc((size_t)N_NODES * 256 * 2);
    unsigned short* out1b= (unsigned short*)alloc((size_t)N_NODES * 256 * 2);
    float* As1    = (float*)alloc((size_t)N_NODES * 4 * 4);
    float* Ad1    = (float*)alloc((size_t)N_NODES * 4 * 4);
    float* As2    = (float*)alloc((size_t)N_NODES * 4);
    float* Ad2    = (float*)alloc((size_t)N_NODES * 4);
    int*   rowptr = (int*)  alloc((size_t)(N_NODES + 1) * 4);
    int*   csrc   = (int*)  alloc((size_t)ETOT_C * 4);
    int2*  ebuf   = (int2*) alloc((size_t)ETOT_C * 8);
    unsigned* bcnt= (unsigned*)alloc((size_t)NBUK * 4);
    int*   bbase  = (int*)  alloc((size_t)(NBUK + 1) * 4);
    unsigned* bcur= (unsigned*)alloc((size_t)NBUK * 4);
    unsigned short* Wt1 = (unsigned short*)alloc((size_t)256 * 128 * 2);
    unsigned short* Wt2 = (unsigned short*)alloc((size_t)64 * 256 * 2);
    float* pooled = (float*)alloc((size_t)N_GRAPHS * 64 * 4);
    float* cntf   = (float*)alloc((size_t)N_GRAPHS * 4);
    unsigned short* h2b = h1b;   // aliases h1b (dead after agg1_k)

    hipMemsetAsync(bcnt, 0, (size_t)NBUK * 4, stream);

    // ---- megaA: passA || cntg || pooled-zero || convw ----
    megaA_k<<<GA + 2 + GZ + GW, 256, 0, stream>>>(dst, bcnt, batch, cntf, pooled,
                                                  W1, W2, Wt1, Wt2);
    scanB_k<<<1, 512, 0, stream>>>(bcnt, bbase, bcur);

    // ---- megaB: gemm1 || passB ----
    megaB_k<<<GB1 + GA, 256, 0, stream>>>(x, Wt1, h1b, as1, ad1, As1, Ad1, N_NODES,
                                          src, dst, bcur, ebuf);
    passC_k<<<NBUK, 256, 0, stream>>>(bbase, ebuf, rowptr, csrc);

    // ---- layer 1 aggregate ----
    agg1_k<<<N_NODES / 4, 256, 0, stream>>>(rowptr, csrc, As1, Ad1,
                                            (const __hip_bfloat16*)h1b, b1, out1b, N_NODES);

    // ---- layer 2 ----
    mfma_gemm2_k<<<(N_NODES + 63) / 64, 256, 0, stream>>>(out1b, Wt2, h2b, as2, ad2,
                                                          As2, Ad2, N_NODES);
    agg2_k<<<N_NODES / 4, 256, 0, stream>>>(rowptr, csrc, As2, Ad2,
                                            (const __hip_bfloat16*)h2b, b2, batch, pooled, N_NODES);

    // ---- head ----
    final_k<<<N_GRAPHS, 64, 0, stream>>>(pooled, cntf, Wl, bl, out);
}